// Round 1
// baseline (324.841 us; speedup 1.0000x reference)
//
#include <hip/hip_runtime.h>

// Problem constants: B=4, S=256, V=50257, D=768
#define BATCH 4
#define SEQ   256
#define VOCAB 50257
#define DIM   768

constexpr int  ROWS   = BATCH * SEQ;                 // 1024
constexpr long TOTAL  = (long)ROWS * VOCAB;          // 51,463,168 (divisible by 4)
constexpr long TOTAL4 = TOTAL / 4;                   // 12,865,792
constexpr int  DIM4   = DIM / 4;                     // 192

// Kernel 1: scan the dense one_hot (as float4) and record the nonzero column per row.
__global__ __launch_bounds__(256) void find_idx_kernel(
    const float4* __restrict__ oh, int* __restrict__ idx) {
    long i = (long)blockIdx.x * blockDim.x + threadIdx.x;
    if (i >= TOTAL4) return;
    float4 v = oh[i];
    // Fast wave-uniform reject path: almost every float4 is all-zero.
    if (v.x != 0.0f || v.y != 0.0f || v.z != 0.0f || v.w != 0.0f) {
        float vals[4] = {v.x, v.y, v.z, v.w};
        long base = i * 4;
        // A float4 can straddle a row boundary (VOCAB is odd) -> resolve each
        // nonzero component independently. Exactly one nonzero per row total,
        // so plain stores (no atomics) are race-free.
        #pragma unroll
        for (int j = 0; j < 4; ++j) {
            if (vals[j] != 0.0f) {
                long flat = base + j;
                int row = (int)(flat / VOCAB);      // rare path: div is fine
                int col = (int)(flat - (long)row * VOCAB);
                idx[row] = col;
            }
        }
    }
}

// Kernel 2: gather weight[idx[row]] -> out[row], float4-coalesced.
__global__ __launch_bounds__(DIM4) void gather_kernel(
    const float4* __restrict__ weight, const int* __restrict__ idx,
    float4* __restrict__ out) {
    int row = blockIdx.x;
    int t   = threadIdx.x;            // 0..191
    int src = idx[row];
    out[(long)row * DIM4 + t] = weight[(long)src * DIM4 + t];
}

extern "C" void kernel_launch(void* const* d_in, const int* in_sizes, int n_in,
                              void* d_out, int out_size, void* d_ws, size_t ws_size,
                              hipStream_t stream) {
    const float4* one_hot = (const float4*)d_in[0];   // [B,S,V] f32
    const float4* weight  = (const float4*)d_in[1];   // [V,D]  f32
    float4* out = (float4*)d_out;                     // [B,S,D] f32
    int* idx = (int*)d_ws;                            // ROWS ints of scratch

    // Phase 1: find indices. TOTAL4 = 12,865,792 = 256 * 50257 exactly.
    int blocksA = (int)((TOTAL4 + 255) / 256);
    find_idx_kernel<<<blocksA, 256, 0, stream>>>(one_hot, idx);

    // Phase 2: gather rows.
    gather_kernel<<<ROWS, DIM4, 0, stream>>>(weight, idx, out);
}